// Round 3
// baseline (158.479 us; speedup 1.0000x reference)
//
#include <hip/hip_runtime.h>
#include <hip/hip_fp16.h>

#define MSAMP 1535
#define NS 1024          // samples computed per ray (covers max chord 887)
#define SPB 32           // samples per block in k_p1
#define NATOMS 229376    // 512 cells * 16 atoms * 28 dims

// ---- kernel 0: fp32 -> fp16 down-convert of atoms table into workspace ----
__global__ __launch_bounds__(256) void k_cvt(const float* __restrict__ a,
                                             __half* __restrict__ ah) {
    int i8 = (blockIdx.x * 256 + threadIdx.x) * 8;
    float4 f0 = *(const float4*)(a + i8);
    float4 f1 = *(const float4*)(a + i8 + 4);
    __half2 h[4];
    h[0] = __floats2half2_rn(f0.x, f0.y);
    h[1] = __floats2half2_rn(f0.z, f0.w);
    h[2] = __floats2half2_rn(f1.x, f1.y);
    h[3] = __floats2half2_rn(f1.z, f1.w);
    *(uint4*)(ah + i8) = *(uint4*)h;
}

// ---- kernel 1: 8 lanes per sample, one corner each, shuffle-reduce ----
__global__ __launch_bounds__(256) void k_p1(const float* __restrict__ ro,
                                            const float* __restrict__ rd,
                                            const float* __restrict__ gridf,
                                            const __half* __restrict__ atomsh,
                                            float* __restrict__ alpha_out,
                                            float4* __restrict__ sig_ws) {
    const float RAD = 1.3f;
    const float STEPF = (float)(1.3 * 2.0 / 32.0 / 8.0 / 2.0);
    int ray = blockIdx.x >> 5;                    // 32 blocks per ray
    int chunk = blockIdx.x & 31;
    int t = threadIdx.x;
    int corner = t & 7;
    int m = chunk * SPB + (t >> 3);

    float ox = ro[ray * 3 + 0], oy = ro[ray * 3 + 1], oz = ro[ray * 3 + 2];
    float dx = rd[ray * 3 + 0], dy = rd[ray * 3 + 1], dz = rd[ray * 3 + 2];

    float a0 = ( RAD - ox) / dx, b0 = (-RAD - ox) / dx;
    float a1 = ( RAD - oy) / dy, b1 = (-RAD - oy) / dy;
    float a2 = ( RAD - oz) / dz, b2 = (-RAD - oz) / dz;
    float st = fmaxf(fmaxf(fminf(a0, b0), fminf(a1, b1)), fminf(a2, b2));

    float tt = st + (float)m * STEPF;
    float px = ox + tt * dx, py = oy + tt * dy, pz = oz + tt * dz;
    int idx = ray * MSAMP + m;
    bool inb = (px > -RAD) && (px < RAD) && (py > -RAD) && (py < RAD) && (pz > -RAD) && (pz < RAD);
    if (!inb) {
        if (corner == 0) alpha_out[idx] = 0.0f;
        return;
    }

    const float inv2R = 1.0f / 2.6f;
    float pnx = fminf(fmaxf((px + RAD) * inv2R, 0.0f), 0.999999f);
    float pny = fminf(fmaxf((py + RAD) * inv2R, 0.0f), 0.999999f);
    float pnz = fminf(fmaxf((pz + RAD) * inv2R, 0.0f), 0.999999f);

    float cpx = pnx * 32.0f, cpy = pny * 32.0f, cpz = pnz * 32.0f;
    float cfx = floorf(cpx), cfy = floorf(cpy), cfz = floorf(cpz);
    int cix = (int)cfx, ciy = (int)cfy, ciz = (int)cfz;

    float fpx = (cpx - cfx) * 8.0f - 0.5f;
    float fpy = (cpy - cfy) * 8.0f - 0.5f;
    float fpz = (cpz - cfz) * 8.0f - 0.5f;
    float ffx = floorf(fpx), ffy = floorf(fpy), ffz = floorf(fpz);
    int f0x = (int)ffx, f0y = (int)ffy, f0z = (int)ffz;
    float wx = fpx - ffx, wy = fpy - ffy, wz = fpz - ffz;

    int cxb = (corner >> 2) & 1, cyb = (corner >> 1) & 1, czb = corner & 1;
    int ix = cxb ? min(f0x + 1, 7) : max(f0x, 0);
    int iy = cyb ? min(f0y + 1, 7) : max(f0y, 0);
    int iz = czb ? min(f0z + 1, 7) : max(f0z, 0);
    float wt = (cxb ? wx : 1.0f - wx) * (cyb ? wy : 1.0f - wy) * (czb ? wz : 1.0f - wz);

    // scaled coefficients: cf[a] = wt * coeff[a]
    const float* cp = gridf + (((cix * 32 + ciy) * 32 + ciz) << 4);
    float cf[16];
    {
        float4 c0 = ((const float4*)cp)[0];
        float4 c1 = ((const float4*)cp)[1];
        float4 c2 = ((const float4*)cp)[2];
        float4 c3 = ((const float4*)cp)[3];
        cf[0]=wt*c0.x; cf[1]=wt*c0.y; cf[2]=wt*c0.z; cf[3]=wt*c0.w;
        cf[4]=wt*c1.x; cf[5]=wt*c1.y; cf[6]=wt*c1.z; cf[7]=wt*c1.w;
        cf[8]=wt*c2.x; cf[9]=wt*c2.y; cf[10]=wt*c2.z; cf[11]=wt*c2.w;
        cf[12]=wt*c3.x; cf[13]=wt*c3.y; cf[14]=wt*c3.z; cf[15]=wt*c3.w;
    }

    float acc[28];
#pragma unroll
    for (int i = 0; i < 28; i++) acc[i] = 0.0f;

    // stream this corner's cell: 448 fp16 = 56 x uint4 (8 halves each)
    const uint4* cell4 = (const uint4*)(atomsh + ((ix * 8 + iy) * 8 + iz) * 448);
#pragma unroll
    for (int k = 0; k < 56; k++) {
        union { uint4 q; __half2 h[4]; } u;
        u.q = cell4[k];
#pragma unroll
        for (int j = 0; j < 4; j++) {
            float2 f = __half22float2(u.h[j]);
            int h0 = k * 8 + j * 2;
            acc[h0 % 28]       = fmaf(cf[h0 / 28],       f.x, acc[h0 % 28]);
            acc[(h0 + 1) % 28] = fmaf(cf[(h0 + 1) / 28], f.y, acc[(h0 + 1) % 28]);
        }
    }

    // reduce the 8 corner-lanes (lanes 8s..8s+7 of the wave)
#pragma unroll
    for (int i = 0; i < 28; i++) {
        acc[i] += __shfl_xor(acc[i], 1);
        acc[i] += __shfl_xor(acc[i], 2);
        acc[i] += __shfl_xor(acc[i], 4);
    }

    if (corner == 0) {
        float nrm = sqrtf(dx * dx + dy * dy + dz * dz);
        float sigma = fmaxf(acc[27], 0.0f);
        float alpha = 1.0f - expf(-sigma * STEPF * nrm);
        alpha_out[idx] = alpha;

        float shm[9];
        shm[0] = 0.28209479177387814f;
        shm[1] = -0.4886025119029199f * dy;
        shm[2] =  0.4886025119029199f * dz;
        shm[3] = -0.4886025119029199f * dx;
        shm[4] =  1.0925484305920792f * dx * dy;
        shm[5] = -1.0925484305920792f * dy * dz;
        shm[6] =  0.31539156525252005f * (2.0f * dz * dz - dx * dx - dy * dy);
        shm[7] = -1.0925484305920792f * dx * dz;
        shm[8] =  0.5462742152960396f * (dx * dx - dy * dy);

        float rgb[3];
#pragma unroll
        for (int kk = 0; kk < 3; kk++) {
            float s = 0.0f;
#pragma unroll
            for (int j = 0; j < 9; j++) s = fmaf(shm[j], acc[kk * 9 + j], s);
            rgb[kk] = 1.0f / (1.0f + expf(-s));
        }
        sig_ws[ray * NS + m] = make_float4(rgb[0], rgb[1], rgb[2], alpha);
    }
}

// ---- kernel 2: per-ray transmittance scan + reductions (shuffle-based) ----
__global__ __launch_bounds__(256) void k_p2(const float* __restrict__ ro,
                                            const float* __restrict__ rd,
                                            const float* __restrict__ alpha_in,
                                            const float4* __restrict__ sig_ws,
                                            float* __restrict__ rgb_out,
                                            float* __restrict__ alpha_tail,
                                            float* __restrict__ depth_out) {
    const float RAD = 1.3f;
    const float STEPF = (float)(1.3 * 2.0 / 32.0 / 8.0 / 2.0);
    int ray = blockIdx.x;
    int t = threadIdx.x;
    int lane = t & 63, wave = t >> 6;

    // zero the alpha tail [1024, 1535)
    int abase = ray * MSAMP;
    for (int m = NS + t; m < MSAMP; m += 256) alpha_tail[abase + m] = 0.0f;

    float ox = ro[ray * 3 + 0], oy = ro[ray * 3 + 1], oz = ro[ray * 3 + 2];
    float dx = rd[ray * 3 + 0], dy = rd[ray * 3 + 1], dz = rd[ray * 3 + 2];
    float a0 = ( RAD - ox) / dx, b0 = (-RAD - ox) / dx;
    float a1 = ( RAD - oy) / dy, b1 = (-RAD - oy) / dy;
    float a2 = ( RAD - oz) / dz, b2 = (-RAD - oz) / dz;
    float st = fmaxf(fmaxf(fminf(a0, b0), fminf(a1, b1)), fminf(a2, b2));

    float av[4];
#pragma unroll
    for (int k = 0; k < 4; k++) av[k] = alpha_in[abase + t * 4 + k];
    float p = 1.0f;
#pragma unroll
    for (int k = 0; k < 4; k++) p *= (1.0f - av[k] + 1e-10f);

    // inclusive product scan over 64 lanes
    float incl = p;
#pragma unroll
    for (int off = 1; off < 64; off <<= 1) {
        float v = __shfl_up(incl, off);
        if (lane >= off) incl *= v;
    }
    __shared__ float wprod[4];
    if (lane == 63) wprod[wave] = incl;
    __syncthreads();
    float excl = __shfl_up(incl, 1);
    if (lane == 0) excl = 1.0f;
    for (int w = 0; w < 4; w++) if (w < wave) excl *= wprod[w];

    float trans = excl;
    float ra = 0.0f, ga = 0.0f, ba = 0.0f, da = 0.0f, wsum = 0.0f;
#pragma unroll
    for (int k = 0; k < 4; k++) {
        int m = t * 4 + k;
        float al = av[k];
        float w = al * trans;
        float4 s = sig_ws[ray * NS + m];
        ra = fmaf(w, s.x, ra);
        ga = fmaf(w, s.y, ga);
        ba = fmaf(w, s.z, ba);
        da = fmaf(w, st + (float)m * STEPF, da);
        wsum += w;
        trans *= (1.0f - al + 1e-10f);
    }

    float vals[5] = { ra, ga, ba, da, wsum };
    __shared__ float wred[4][5];
#pragma unroll
    for (int i = 0; i < 5; i++) {
        float v = vals[i];
        v += __shfl_xor(v, 1);  v += __shfl_xor(v, 2);  v += __shfl_xor(v, 4);
        v += __shfl_xor(v, 8);  v += __shfl_xor(v, 16); v += __shfl_xor(v, 32);
        if (lane == 0) wred[wave][i] = v;
    }
    __syncthreads();
    if (t == 0) {
        float res[5];
#pragma unroll
        for (int i = 0; i < 5; i++)
            res[i] = wred[0][i] + wred[1][i] + wred[2][i] + wred[3][i];
        float omw = 1.0f - res[4];
        rgb_out[ray * 3 + 0] = res[0] + omw;
        rgb_out[ray * 3 + 1] = res[1] + omw;
        rgb_out[ray * 3 + 2] = res[2] + omw;
        depth_out[ray] = res[3];
    }
}

extern "C" void kernel_launch(void* const* d_in, const int* in_sizes, int n_in,
                              void* d_out, int out_size, void* d_ws, size_t ws_size,
                              hipStream_t stream) {
    const float* ro    = (const float*)d_in[0];
    const float* rd    = (const float*)d_in[1];
    const float* grid  = (const float*)d_in[2];
    const float* atoms = (const float*)d_in[3];
    int B = in_sizes[0] / 3;  // 128

    __half* atomsh = (__half*)d_ws;                       // 458752 B
    float4* sig    = (float4*)((char*)d_ws + NATOMS * 2); // 2 MB

    float* out       = (float*)d_out;
    float* rgb_out   = out;
    float* alpha_out = out + B * 3;
    float* depth_out = out + B * 3 + B * MSAMP;

    hipLaunchKernelGGL(k_cvt, dim3(NATOMS / 8 / 256), dim3(256), 0, stream,
                       atoms, atomsh);
    hipLaunchKernelGGL(k_p1, dim3(B * 32), dim3(256), 0, stream,
                       ro, rd, grid, atomsh, alpha_out, sig);
    hipLaunchKernelGGL(k_p2, dim3(B), dim3(256), 0, stream,
                       ro, rd, alpha_out, sig, rgb_out, alpha_out, depth_out);
}

// Round 4
// 99.075 us; speedup vs baseline: 1.5996x; 1.5996x over previous
//
#include <hip/hip_runtime.h>
#include <hip/hip_fp16.h>

typedef unsigned int u32;

#define MSAMP 1535
#define NS 1024          // samples computed per ray (max chord = 887)
#define RADF 1.3f
#define STEPF ((float)(1.3 * 2.0 / 32.0 / 8.0 / 2.0))

// ---- k_t: transpose atoms fp32 [512 cell][16 a][28 d] -> fp16 [7 s][512 cell][4 j][16 a]
__global__ __launch_bounds__(256) void k_t(const float* __restrict__ atoms,
                                           __half* __restrict__ wst) {
    int o = blockIdx.x * 256 + threadIdx.x;   // 229376 total
    int s = o >> 15;
    int r = o & 32767;
    int cell = r >> 6;
    int j = (r >> 4) & 3;
    int a = r & 15;
    wst[o] = __float2half(atoms[(cell * 16 + a) * 28 + s * 4 + j]);
}

// ---- k_p1: block = (slice s, ray); atoms slice in LDS; thread = sample ----
__global__ __launch_bounds__(512) void k_p1(const float* __restrict__ ro,
                                            const float* __restrict__ rd,
                                            const float* __restrict__ gridf,
                                            const __half* __restrict__ wst,
                                            __half* __restrict__ raw) {
    // 512 cells * 68 halfs (64 data + 4 pad) = 69,632 B; stride 136 B == 34 dw
    // -> 34 mod 32 = 2: cells c and c+16 alias (2-way, free per m136)
    __shared__ __half hl[512 * 68];
    int bx = blockIdx.x;
    int s   = bx >> 7;    // slice 0..6
    int ray = bx & 127;
    int tid = threadIdx.x;

    {   // stage 64 KB slice, coalesced uint2 (4 halfs) chunks
        const uint2* src = (const uint2*)(wst + s * 32768);
#pragma unroll
        for (int it = 0; it < 16; it++) {
            int idx = it * 512 + tid;          // uint2 index
            uint2 v = src[idx];
            int cell  = idx >> 4;
            int inner = (idx & 15) << 2;       // half offset within cell
            *(uint2*)&hl[cell * 68 + inner] = v;
        }
    }
    __syncthreads();

    float ox = ro[ray * 3 + 0], oy = ro[ray * 3 + 1], oz = ro[ray * 3 + 2];
    float dx = rd[ray * 3 + 0], dy = rd[ray * 3 + 1], dz = rd[ray * 3 + 2];
    float a0 = ( RADF - ox) / dx, b0 = (-RADF - ox) / dx;
    float a1 = ( RADF - oy) / dy, b1 = (-RADF - oy) / dy;
    float a2 = ( RADF - oz) / dz, b2 = (-RADF - oz) / dz;
    float st = fmaxf(fmaxf(fminf(a0, b0), fminf(a1, b1)), fminf(a2, b2));

    for (int m = tid; m < NS; m += 512) {
        float t = st + (float)m * STEPF;
        float px = ox + t * dx, py = oy + t * dy, pz = oz + t * dz;
        bool inb = (px > -RADF) && (px < RADF) && (py > -RADF) && (py < RADF)
                && (pz > -RADF) && (pz < RADF);
        if (!inb) continue;

        const float inv2R = 1.0f / 2.6f;
        float pnx = fminf(fmaxf((px + RADF) * inv2R, 0.0f), 0.999999f);
        float pny = fminf(fmaxf((py + RADF) * inv2R, 0.0f), 0.999999f);
        float pnz = fminf(fmaxf((pz + RADF) * inv2R, 0.0f), 0.999999f);

        float cpx = pnx * 32.0f, cpy = pny * 32.0f, cpz = pnz * 32.0f;
        float cfx = floorf(cpx), cfy = floorf(cpy), cfz = floorf(cpz);
        int cix = (int)cfx, ciy = (int)cfy, ciz = (int)cfz;

        float fpx = (cpx - cfx) * 8.0f - 0.5f;
        float fpy = (cpy - cfy) * 8.0f - 0.5f;
        float fpz = (cpz - cfz) * 8.0f - 0.5f;
        float ffx = floorf(fpx), ffy = floorf(fpy), ffz = floorf(fpz);
        int f0x = (int)ffx, f0y = (int)ffy, f0z = (int)ffz;
        float wx = fpx - ffx, wy = fpy - ffy, wz = fpz - ffz;

        int ixa[2] = { max(f0x, 0), min(f0x + 1, 7) };
        int iya[2] = { max(f0y, 0), min(f0y + 1, 7) };
        int iza[2] = { max(f0z, 0), min(f0z + 1, 7) };
        float wxa[2] = { 1.0f - wx, wx };
        float wya[2] = { 1.0f - wy, wy };
        float wza[2] = { 1.0f - wz, wz };

        float c[16];
        {
            const float4* cp = (const float4*)(gridf + (((cix * 32 + ciy) * 32 + ciz) << 4));
            float4 c0 = cp[0], c1 = cp[1], c2 = cp[2], c3 = cp[3];
            c[0]=c0.x; c[1]=c0.y; c[2]=c0.z; c[3]=c0.w;
            c[4]=c1.x; c[5]=c1.y; c[6]=c1.z; c[7]=c1.w;
            c[8]=c2.x; c[9]=c2.y; c[10]=c2.z; c[11]=c2.w;
            c[12]=c3.x; c[13]=c3.y; c[14]=c3.z; c[15]=c3.w;
        }

        float acc[4] = {0.0f, 0.0f, 0.0f, 0.0f};

#pragma unroll
        for (int cx = 0; cx < 2; cx++)
#pragma unroll
        for (int cy = 0; cy < 2; cy++)
#pragma unroll
        for (int cz = 0; cz < 2; cz++) {
            float wt = wxa[cx] * wya[cy] * wza[cz];
            int cb = ((ixa[cx] * 8 + iya[cy]) * 8 + iza[cz]) * 68;
            float dd[4] = {0.0f, 0.0f, 0.0f, 0.0f};
#pragma unroll
            for (int g = 0; g < 4; g++) {
#pragma unroll
                for (int j = 0; j < 4; j++) {
                    uint2 q = *(const uint2*)&hl[cb + j * 16 + g * 4];
                    __half2 h0 = *(__half2*)&q.x;
                    __half2 h1 = *(__half2*)&q.y;
                    float2 f0v = __half22float2(h0);
                    float2 f1v = __half22float2(h1);
                    float r_ = fmaf(c[g*4+0], f0v.x,
                               fmaf(c[g*4+1], f0v.y,
                               fmaf(c[g*4+2], f1v.x,
                                    c[g*4+3] * f1v.y)));
                    dd[j] += r_;
                }
            }
#pragma unroll
            for (int j = 0; j < 4; j++) acc[j] = fmaf(wt, dd[j], acc[j]);
        }

        __half2 p0 = __floats2half2_rn(acc[0], acc[1]);
        __half2 p1 = __floats2half2_rn(acc[2], acc[3]);
        uint2 pv;
        pv.x = *(u32*)&p0;
        pv.y = *(u32*)&p1;
        *(uint2*)&raw[(ray * NS + m) * 28 + s * 4] = pv;
    }
}

// ---- k_p2: per-ray SH-dot + sigmoid + alpha + transmittance scan + reductions ----
__global__ __launch_bounds__(256) void k_p2(const float* __restrict__ ro,
                                            const float* __restrict__ rd,
                                            const __half* __restrict__ raw,
                                            float* __restrict__ rgb_out,
                                            float* __restrict__ alpha_out,
                                            float* __restrict__ depth_out) {
    int ray = blockIdx.x;
    int t = threadIdx.x;
    int lane = t & 63, wave = t >> 6;

    int abase = ray * MSAMP;
    for (int m = NS + t; m < MSAMP; m += 256) alpha_out[abase + m] = 0.0f;

    float ox = ro[ray * 3 + 0], oy = ro[ray * 3 + 1], oz = ro[ray * 3 + 2];
    float dx = rd[ray * 3 + 0], dy = rd[ray * 3 + 1], dz = rd[ray * 3 + 2];
    float a0 = ( RADF - ox) / dx, b0 = (-RADF - ox) / dx;
    float a1 = ( RADF - oy) / dy, b1 = (-RADF - oy) / dy;
    float a2 = ( RADF - oz) / dz, b2 = (-RADF - oz) / dz;
    float st = fmaxf(fmaxf(fminf(a0, b0), fminf(a1, b1)), fminf(a2, b2));
    float nrm = sqrtf(dx * dx + dy * dy + dz * dz);

    float shm[9];
    shm[0] = 0.28209479177387814f;
    shm[1] = -0.4886025119029199f * dy;
    shm[2] =  0.4886025119029199f * dz;
    shm[3] = -0.4886025119029199f * dx;
    shm[4] =  1.0925484305920792f * dx * dy;
    shm[5] = -1.0925484305920792f * dy * dz;
    shm[6] =  0.31539156525252005f * (2.0f * dz * dz - dx * dx - dy * dy);
    shm[7] = -1.0925484305920792f * dx * dz;
    shm[8] =  0.5462742152960396f * (dx * dx - dy * dy);

    float av[4], sr[4], sg[4], sb[4];
#pragma unroll
    for (int k = 0; k < 4; k++) {
        int m = t * 4 + k;
        float tm = st + (float)m * STEPF;
        float px = ox + tm * dx, py = oy + tm * dy, pz = oz + tm * dz;
        bool inb = (px > -RADF) && (px < RADF) && (py > -RADF) && (py < RADF)
                && (pz > -RADF) && (pz < RADF);
        float alpha = 0.0f, r0 = 0.0f, r1 = 0.0f, r2 = 0.0f;
        if (inb) {
            const __half* rp = raw + (ray * NS + m) * 28;
            float v[28];
#pragma unroll
            for (int i = 0; i < 7; i++) {
                uint2 q = *(const uint2*)(rp + i * 4);
                __half2 h0 = *(__half2*)&q.x;
                __half2 h1 = *(__half2*)&q.y;
                float2 f0v = __half22float2(h0);
                float2 f1v = __half22float2(h1);
                v[i*4+0] = f0v.x; v[i*4+1] = f0v.y; v[i*4+2] = f1v.x; v[i*4+3] = f1v.y;
            }
            float sigma = fmaxf(v[27], 0.0f);
            alpha = 1.0f - __expf(-sigma * STEPF * nrm);
            float rr[3];
#pragma unroll
            for (int cch = 0; cch < 3; cch++) {
                float sdot = 0.0f;
#pragma unroll
                for (int j = 0; j < 9; j++) sdot = fmaf(shm[j], v[cch * 9 + j], sdot);
                rr[cch] = 1.0f / (1.0f + __expf(-sdot));
            }
            r0 = rr[0]; r1 = rr[1]; r2 = rr[2];
        }
        av[k] = alpha; sr[k] = r0; sg[k] = r1; sb[k] = r2;
        alpha_out[abase + m] = alpha;
    }

    float p = 1.0f;
#pragma unroll
    for (int k = 0; k < 4; k++) p *= (1.0f - av[k] + 1e-10f);

    float incl = p;
#pragma unroll
    for (int off = 1; off < 64; off <<= 1) {
        float vv = __shfl_up(incl, off);
        if (lane >= off) incl *= vv;
    }
    __shared__ float wprod[4];
    if (lane == 63) wprod[wave] = incl;
    __syncthreads();
    float excl = __shfl_up(incl, 1);
    if (lane == 0) excl = 1.0f;
    for (int w = 0; w < 4; w++) if (w < wave) excl *= wprod[w];

    float trans = excl;
    float ra = 0.0f, ga = 0.0f, ba = 0.0f, da = 0.0f, wsum = 0.0f;
#pragma unroll
    for (int k = 0; k < 4; k++) {
        int m = t * 4 + k;
        float al = av[k];
        float w = al * trans;
        ra = fmaf(w, sr[k], ra);
        ga = fmaf(w, sg[k], ga);
        ba = fmaf(w, sb[k], ba);
        da = fmaf(w, st + (float)m * STEPF, da);
        wsum += w;
        trans *= (1.0f - al + 1e-10f);
    }

    float vals[5] = { ra, ga, ba, da, wsum };
    __shared__ float wred[4][5];
#pragma unroll
    for (int i = 0; i < 5; i++) {
        float v = vals[i];
        v += __shfl_xor(v, 1);  v += __shfl_xor(v, 2);  v += __shfl_xor(v, 4);
        v += __shfl_xor(v, 8);  v += __shfl_xor(v, 16); v += __shfl_xor(v, 32);
        if (lane == 0) wred[wave][i] = v;
    }
    __syncthreads();
    if (t == 0) {
        float res[5];
#pragma unroll
        for (int i = 0; i < 5; i++)
            res[i] = wred[0][i] + wred[1][i] + wred[2][i] + wred[3][i];
        float omw = 1.0f - res[4];
        rgb_out[ray * 3 + 0] = res[0] + omw;
        rgb_out[ray * 3 + 1] = res[1] + omw;
        rgb_out[ray * 3 + 2] = res[2] + omw;
        depth_out[ray] = res[3];
    }
}

extern "C" void kernel_launch(void* const* d_in, const int* in_sizes, int n_in,
                              void* d_out, int out_size, void* d_ws, size_t ws_size,
                              hipStream_t stream) {
    const float* ro    = (const float*)d_in[0];
    const float* rd    = (const float*)d_in[1];
    const float* grid  = (const float*)d_in[2];
    const float* atoms = (const float*)d_in[3];
    int B = in_sizes[0] / 3;  // 128

    __half* wst = (__half*)d_ws;                             // 229,376 halfs = 458,752 B
    __half* raw = (__half*)((char*)d_ws + 458752);           // 128*1024*28 halfs = 7,340,032 B

    float* out       = (float*)d_out;
    float* rgb_out   = out;
    float* alpha_out = out + B * 3;
    float* depth_out = out + B * 3 + B * MSAMP;

    hipLaunchKernelGGL(k_t,  dim3(896), dim3(256), 0, stream, atoms, wst);
    hipLaunchKernelGGL(k_p1, dim3(896), dim3(512), 0, stream, ro, rd, grid, wst, raw);
    hipLaunchKernelGGL(k_p2, dim3(B),   dim3(256), 0, stream, ro, rd, raw,
                       rgb_out, alpha_out, depth_out);
}

// Round 5
// 86.888 us; speedup vs baseline: 1.8240x; 1.1403x over previous
//
#include <hip/hip_runtime.h>
#include <hip/hip_fp16.h>

typedef unsigned int u32;
typedef _Float16 half2v __attribute__((ext_vector_type(2)));
union H2 { u32 u; half2v v; };

#define MSAMP 1535
#define NS 1024          // samples computed per ray (max chord = 887)
#define RADF 1.3f
#define STEPF ((float)(1.3 * 2.0 / 32.0 / 8.0 / 2.0))

// ---- k_t: transpose atoms fp32 [512 cell][16 a][28 d] -> fp16 [7 s][512 cell][4 j][16 a]
__global__ __launch_bounds__(256) void k_t(const float* __restrict__ atoms,
                                           __half* __restrict__ wst) {
    int o = blockIdx.x * 256 + threadIdx.x;   // 229376 total
    int s = o >> 15;
    int r = o & 32767;
    int cell = r >> 6;
    int j = (r >> 4) & 3;
    int a = r & 15;
    wst[o] = __float2half(atoms[(cell * 16 + a) * 28 + s * 4 + j]);
}

// ---- k_p1: block = (slice s, ray); atoms slice in LDS; thread = sample ----
__global__ __launch_bounds__(512) void k_p1(const float* __restrict__ ro,
                                            const float* __restrict__ rd,
                                            const float* __restrict__ gridf,
                                            const __half* __restrict__ wst,
                                            __half* __restrict__ raw) {
    // 512 cells * 68 halfs (64 data + 4 pad) = 69,632 B; stride 136 B == 34 dw
    // -> 34 mod 32 = 2: cells c and c+16 alias (2-way, free per m136)
    __shared__ __half hl[512 * 68];
    int bx = blockIdx.x;
    int s   = bx >> 7;    // slice 0..6
    int ray = bx & 127;
    int tid = threadIdx.x;

    {   // stage 64 KB slice, coalesced uint2 (4 halfs) chunks
        const uint2* src = (const uint2*)(wst + s * 32768);
#pragma unroll
        for (int it = 0; it < 16; it++) {
            int idx = it * 512 + tid;          // uint2 index
            uint2 v = src[idx];
            int cell  = idx >> 4;
            int inner = (idx & 15) << 2;       // half offset within cell
            *(uint2*)&hl[cell * 68 + inner] = v;
        }
    }
    __syncthreads();

    float ox = ro[ray * 3 + 0], oy = ro[ray * 3 + 1], oz = ro[ray * 3 + 2];
    float dx = rd[ray * 3 + 0], dy = rd[ray * 3 + 1], dz = rd[ray * 3 + 2];
    float a0 = ( RADF - ox) / dx, b0 = (-RADF - ox) / dx;
    float a1 = ( RADF - oy) / dy, b1 = (-RADF - oy) / dy;
    float a2 = ( RADF - oz) / dz, b2 = (-RADF - oz) / dz;
    float st = fmaxf(fmaxf(fminf(a0, b0), fminf(a1, b1)), fminf(a2, b2));

    for (int m = tid; m < NS; m += 512) {
        float t = st + (float)m * STEPF;
        float px = ox + t * dx, py = oy + t * dy, pz = oz + t * dz;
        bool inb = (px > -RADF) && (px < RADF) && (py > -RADF) && (py < RADF)
                && (pz > -RADF) && (pz < RADF);
        if (!inb) continue;

        const float inv2R = 1.0f / 2.6f;
        float pnx = fminf(fmaxf((px + RADF) * inv2R, 0.0f), 0.999999f);
        float pny = fminf(fmaxf((py + RADF) * inv2R, 0.0f), 0.999999f);
        float pnz = fminf(fmaxf((pz + RADF) * inv2R, 0.0f), 0.999999f);

        float cpx = pnx * 32.0f, cpy = pny * 32.0f, cpz = pnz * 32.0f;
        float cfx = floorf(cpx), cfy = floorf(cpy), cfz = floorf(cpz);
        int cix = (int)cfx, ciy = (int)cfy, ciz = (int)cfz;

        float fpx = (cpx - cfx) * 8.0f - 0.5f;
        float fpy = (cpy - cfy) * 8.0f - 0.5f;
        float fpz = (cpz - cfz) * 8.0f - 0.5f;
        float ffx = floorf(fpx), ffy = floorf(fpy), ffz = floorf(fpz);
        int f0x = (int)ffx, f0y = (int)ffy, f0z = (int)ffz;
        float wx = fpx - ffx, wy = fpy - ffy, wz = fpz - ffz;

        int ixa[2] = { max(f0x, 0), min(f0x + 1, 7) };
        int iya[2] = { max(f0y, 0), min(f0y + 1, 7) };
        int iza[2] = { max(f0z, 0), min(f0z + 1, 7) };
        float wxa[2] = { 1.0f - wx, wx };
        float wya[2] = { 1.0f - wy, wy };
        float wza[2] = { 1.0f - wz, wz };

        // grid coeffs packed as 8 half2
        half2v ch[8];
        {
            const float4* cp = (const float4*)(gridf + (((cix * 32 + ciy) * 32 + ciz) << 4));
            float4 c0 = cp[0], c1 = cp[1], c2 = cp[2], c3 = cp[3];
            ch[0] = half2v{(_Float16)c0.x, (_Float16)c0.y};
            ch[1] = half2v{(_Float16)c0.z, (_Float16)c0.w};
            ch[2] = half2v{(_Float16)c1.x, (_Float16)c1.y};
            ch[3] = half2v{(_Float16)c1.z, (_Float16)c1.w};
            ch[4] = half2v{(_Float16)c2.x, (_Float16)c2.y};
            ch[5] = half2v{(_Float16)c2.z, (_Float16)c2.w};
            ch[6] = half2v{(_Float16)c3.x, (_Float16)c3.y};
            ch[7] = half2v{(_Float16)c3.z, (_Float16)c3.w};
        }

        float acc[4] = {0.0f, 0.0f, 0.0f, 0.0f};

#pragma unroll
        for (int cx = 0; cx < 2; cx++)
#pragma unroll
        for (int cy = 0; cy < 2; cy++)
#pragma unroll
        for (int cz = 0; cz < 2; cz++) {
            float wt = wxa[cx] * wya[cy] * wza[cz];
            int cb = ((ixa[cx] * 8 + iya[cy]) * 8 + iza[cz]) * 68;
            float dd[4] = {0.0f, 0.0f, 0.0f, 0.0f};
#pragma unroll
            for (int g = 0; g < 4; g++) {
#pragma unroll
                for (int j = 0; j < 4; j++) {
                    uint2 q = *(const uint2*)&hl[cb + j * 16 + g * 4];
                    H2 a0h, a1h; a0h.u = q.x; a1h.u = q.y;
                    dd[j] = __builtin_amdgcn_fdot2(a0h.v, ch[2 * g],     dd[j], false);
                    dd[j] = __builtin_amdgcn_fdot2(a1h.v, ch[2 * g + 1], dd[j], false);
                }
            }
#pragma unroll
            for (int j = 0; j < 4; j++) acc[j] = fmaf(wt, dd[j], acc[j]);
        }

        __half2 p0 = __floats2half2_rn(acc[0], acc[1]);
        __half2 p1 = __floats2half2_rn(acc[2], acc[3]);
        uint2 pv;
        pv.x = *(u32*)&p0;
        pv.y = *(u32*)&p1;
        *(uint2*)&raw[(ray * NS + m) * 28 + s * 4] = pv;
    }
}

// ---- k_p2: per-ray SH-dot + sigmoid + alpha + transmittance scan + reductions ----
__global__ __launch_bounds__(512) void k_p2(const float* __restrict__ ro,
                                            const float* __restrict__ rd,
                                            const __half* __restrict__ raw,
                                            float* __restrict__ rgb_out,
                                            float* __restrict__ alpha_out,
                                            float* __restrict__ depth_out) {
    int ray = blockIdx.x;
    int t = threadIdx.x;
    int lane = t & 63, wave = t >> 6;

    int abase = ray * MSAMP;
    for (int m = NS + t; m < MSAMP; m += 512) alpha_out[abase + m] = 0.0f;

    float ox = ro[ray * 3 + 0], oy = ro[ray * 3 + 1], oz = ro[ray * 3 + 2];
    float dx = rd[ray * 3 + 0], dy = rd[ray * 3 + 1], dz = rd[ray * 3 + 2];
    float a0 = ( RADF - ox) / dx, b0 = (-RADF - ox) / dx;
    float a1 = ( RADF - oy) / dy, b1 = (-RADF - oy) / dy;
    float a2 = ( RADF - oz) / dz, b2 = (-RADF - oz) / dz;
    float st = fmaxf(fmaxf(fminf(a0, b0), fminf(a1, b1)), fminf(a2, b2));
    float nrm = sqrtf(dx * dx + dy * dy + dz * dz);

    float shm[9];
    shm[0] = 0.28209479177387814f;
    shm[1] = -0.4886025119029199f * dy;
    shm[2] =  0.4886025119029199f * dz;
    shm[3] = -0.4886025119029199f * dx;
    shm[4] =  1.0925484305920792f * dx * dy;
    shm[5] = -1.0925484305920792f * dy * dz;
    shm[6] =  0.31539156525252005f * (2.0f * dz * dz - dx * dx - dy * dy);
    shm[7] = -1.0925484305920792f * dx * dz;
    shm[8] =  0.5462742152960396f * (dx * dx - dy * dy);

    float av[2], sr[2], sg[2], sb[2];
#pragma unroll
    for (int k = 0; k < 2; k++) {
        int m = t * 2 + k;
        float tm = st + (float)m * STEPF;
        float px = ox + tm * dx, py = oy + tm * dy, pz = oz + tm * dz;
        bool inb = (px > -RADF) && (px < RADF) && (py > -RADF) && (py < RADF)
                && (pz > -RADF) && (pz < RADF);
        float alpha = 0.0f, r0 = 0.0f, r1 = 0.0f, r2 = 0.0f;
        if (inb) {
            const __half* rp = raw + (ray * NS + m) * 28;
            float v[28];
#pragma unroll
            for (int i = 0; i < 7; i++) {
                uint2 q = *(const uint2*)(rp + i * 4);
                __half2 h0 = *(__half2*)&q.x;
                __half2 h1 = *(__half2*)&q.y;
                float2 f0v = __half22float2(h0);
                float2 f1v = __half22float2(h1);
                v[i*4+0] = f0v.x; v[i*4+1] = f0v.y; v[i*4+2] = f1v.x; v[i*4+3] = f1v.y;
            }
            float sigma = fmaxf(v[27], 0.0f);
            alpha = 1.0f - __expf(-sigma * STEPF * nrm);
            float rr[3];
#pragma unroll
            for (int cch = 0; cch < 3; cch++) {
                float sdot = 0.0f;
#pragma unroll
                for (int j = 0; j < 9; j++) sdot = fmaf(shm[j], v[cch * 9 + j], sdot);
                rr[cch] = 1.0f / (1.0f + __expf(-sdot));
            }
            r0 = rr[0]; r1 = rr[1]; r2 = rr[2];
        }
        av[k] = alpha; sr[k] = r0; sg[k] = r1; sb[k] = r2;
        alpha_out[abase + m] = alpha;
    }

    float p = (1.0f - av[0] + 1e-10f) * (1.0f - av[1] + 1e-10f);

    float incl = p;
#pragma unroll
    for (int off = 1; off < 64; off <<= 1) {
        float vv = __shfl_up(incl, off);
        if (lane >= off) incl *= vv;
    }
    __shared__ float wprod[8];
    if (lane == 63) wprod[wave] = incl;
    __syncthreads();
    float excl = __shfl_up(incl, 1);
    if (lane == 0) excl = 1.0f;
    for (int w = 0; w < 8; w++) if (w < wave) excl *= wprod[w];

    float trans = excl;
    float ra = 0.0f, ga = 0.0f, ba = 0.0f, da = 0.0f, wsum = 0.0f;
#pragma unroll
    for (int k = 0; k < 2; k++) {
        int m = t * 2 + k;
        float al = av[k];
        float w = al * trans;
        ra = fmaf(w, sr[k], ra);
        ga = fmaf(w, sg[k], ga);
        ba = fmaf(w, sb[k], ba);
        da = fmaf(w, st + (float)m * STEPF, da);
        wsum += w;
        trans *= (1.0f - al + 1e-10f);
    }

    float vals[5] = { ra, ga, ba, da, wsum };
    __shared__ float wred[8][5];
#pragma unroll
    for (int i = 0; i < 5; i++) {
        float v = vals[i];
        v += __shfl_xor(v, 1);  v += __shfl_xor(v, 2);  v += __shfl_xor(v, 4);
        v += __shfl_xor(v, 8);  v += __shfl_xor(v, 16); v += __shfl_xor(v, 32);
        if (lane == 0) wred[wave][i] = v;
    }
    __syncthreads();
    if (t == 0) {
        float res[5];
#pragma unroll
        for (int i = 0; i < 5; i++) {
            float r_ = 0.0f;
            for (int w = 0; w < 8; w++) r_ += wred[w][i];
            res[i] = r_;
        }
        float omw = 1.0f - res[4];
        rgb_out[ray * 3 + 0] = res[0] + omw;
        rgb_out[ray * 3 + 1] = res[1] + omw;
        rgb_out[ray * 3 + 2] = res[2] + omw;
        depth_out[ray] = res[3];
    }
}

extern "C" void kernel_launch(void* const* d_in, const int* in_sizes, int n_in,
                              void* d_out, int out_size, void* d_ws, size_t ws_size,
                              hipStream_t stream) {
    const float* ro    = (const float*)d_in[0];
    const float* rd    = (const float*)d_in[1];
    const float* grid  = (const float*)d_in[2];
    const float* atoms = (const float*)d_in[3];
    int B = in_sizes[0] / 3;  // 128

    __half* wst = (__half*)d_ws;                             // 229,376 halfs = 458,752 B
    __half* raw = (__half*)((char*)d_ws + 458752);           // 128*1024*28 halfs = 7,340,032 B

    float* out       = (float*)d_out;
    float* rgb_out   = out;
    float* alpha_out = out + B * 3;
    float* depth_out = out + B * 3 + B * MSAMP;

    hipLaunchKernelGGL(k_t,  dim3(896), dim3(256), 0, stream, atoms, wst);
    hipLaunchKernelGGL(k_p1, dim3(896), dim3(512), 0, stream, ro, rd, grid, wst, raw);
    hipLaunchKernelGGL(k_p2, dim3(B),   dim3(512), 0, stream, ro, rd, raw,
                       rgb_out, alpha_out, depth_out);
}